// Round 1
// baseline (68.956 us; speedup 1.0000x reference)
//
#include <hip/hip_runtime.h>
#include <hip/hip_bf16.h>

typedef __bf16 bf16x8 __attribute__((ext_vector_type(8)));
typedef float  f32x4  __attribute__((ext_vector_type(4)));

#define MFMA16(a,b,c) __builtin_amdgcn_mfma_f32_16x16x32_bf16((a),(b),(c),0,0,0)

constexpr int Bn = 8192, Dd = 64, Hh = 128, MT = 32;

__device__ __forceinline__ unsigned short f2bf(float f) {
    unsigned int u = __builtin_bit_cast(unsigned int, f);
    u = (u + 0x7FFFu + ((u >> 16) & 1u)) >> 16;   // RNE
    return (unsigned short)u;
}

__device__ __forceinline__ bf16x8 ld8(const unsigned short* p) {
    return *(const bf16x8*)p;   // 16B-aligned by construction -> ds_read_b128
}

// LDS layout (ushort units), all row pitches give 16B-aligned b128 reads
// and <=2-way bank aliasing (free per m136):
//   W1b [128][72] @0      (GEMM1 B-frags, row-major W1[j][d])
//   Wfb [64][72]  @9216   (GEMM3 B-frags, row-major Wf[i][d])
//   Zb  [32][72]  @13824  (A-frags for GEMM1/3)
//   W1T [64][136] @16128  (GEMM2 B-frags, W1T[d][j])
//   Gb  [32][136] @24832  (GEMM2 A-frags, row-major G[r][j])
__global__ __launch_bounds__(256) void gnl_kernel(
    const float* __restrict__ z, const float* __restrict__ W1,
    const float* __restrict__ b1, const float* __restrict__ W2,
    const float* __restrict__ Wf, float* __restrict__ out)
{
    __shared__ unsigned short sh[29184];
    __shared__ float b1f[128];
    __shared__ float w2f[128];
    unsigned short* W1b = sh;
    unsigned short* Wfb = sh + 9216;
    unsigned short* Zb  = sh + 13824;
    unsigned short* W1T = sh + 16128;
    unsigned short* Gb  = sh + 24832;

    const int tid  = threadIdx.x;
    const int row0 = blockIdx.x * MT;

    // ---- stage weights + z tile (fp32 -> bf16) ----
    {
        const float4* gv = (const float4*)W1;                 // 2048 float4
        for (int i = tid; i < (Hh * Dd) / 4; i += 256) {
            float4 v = gv[i];
            int e = i << 2, j = e >> 6, d = e & 63;
            unsigned short c0 = f2bf(v.x), c1 = f2bf(v.y), c2 = f2bf(v.z), c3 = f2bf(v.w);
            *(ushort4*)(W1b + j * 72 + d) = make_ushort4(c0, c1, c2, c3);
            W1T[(d + 0) * 136 + j] = c0;                      // transpose for GEMM2
            W1T[(d + 1) * 136 + j] = c1;
            W1T[(d + 2) * 136 + j] = c2;
            W1T[(d + 3) * 136 + j] = c3;
        }
        gv = (const float4*)Wf;                               // 1024 float4
        for (int i = tid; i < (Dd * Dd) / 4; i += 256) {
            float4 v = gv[i];
            int e = i << 2, j = e >> 6, d = e & 63;
            *(ushort4*)(Wfb + j * 72 + d) =
                make_ushort4(f2bf(v.x), f2bf(v.y), f2bf(v.z), f2bf(v.w));
        }
        gv = (const float4*)(z + (size_t)row0 * Dd);          // 512 float4
        for (int i = tid; i < (MT * Dd) / 4; i += 256) {
            float4 v = gv[i];
            int e = i << 2, r = e >> 6, d = e & 63;
            *(ushort4*)(Zb + r * 72 + d) =
                make_ushort4(f2bf(v.x), f2bf(v.y), f2bf(v.z), f2bf(v.w));
        }
        if (tid < 128) { b1f[tid] = b1[tid]; w2f[tid] = W2[tid]; }
    }
    __syncthreads();

    const int lane = tid & 63, w = tid >> 6;
    const int l15 = lane & 15, q = lane >> 4;
    const int mt = w & 1;                                     // 16-row sub-tile

    // A-frags from Z: A[m=lane&15][k=quad*8+j], reused by GEMM1 and GEMM3
    const int zoff = (mt * 16 + l15) * 72 + q * 8;
    bf16x8 za0 = ld8(Zb + zoff);
    bf16x8 za1 = ld8(Zb + zoff + 32);

    // ---- GEMM1: U = Z*W1^T (K=64), fused g = W2*silu'(u+b1) -> Gb ----
    {
        const int ntb = (w >> 1) * 4;                         // 4 N-tiles per wave
        for (int nt = 0; nt < 4; ++nt) {
            const int jc = (ntb + nt) * 16 + l15;             // column j of U
            const unsigned short* wp = W1b + jc * 72 + q * 8; // B[k=d][n=j]=W1[j][d]
            f32x4 acc = {0.f, 0.f, 0.f, 0.f};
            acc = MFMA16(za0, ld8(wp), acc);
            acc = MFMA16(za1, ld8(wp + 32), acc);
            const float bj = b1f[jc], w2j = w2f[jc];
            #pragma unroll
            for (int r = 0; r < 4; ++r) {                     // C: row=q*4+r, col=jc
                float u = acc[r] + bj;
                float s = 1.f / (1.f + __expf(-u));
                float g = w2j * (s * (1.f + u * (1.f - s))); // W2 * silu'(u)
                Gb[(mt * 16 + q * 4 + r) * 136 + jc] = f2bf(g);
            }
        }
    }
    __syncthreads();

    // ---- GEMM2: GS = G*W1 (K=128) ; GEMM3: A = Z*Wf^T (K=64) ; epilogue ----
    {
        const int goff = (mt * 16 + l15) * 136 + q * 8;
        bf16x8 ga0 = ld8(Gb + goff);
        bf16x8 ga1 = ld8(Gb + goff + 32);
        bf16x8 ga2 = ld8(Gb + goff + 64);
        bf16x8 ga3 = ld8(Gb + goff + 96);
        const int ntb = (w >> 1) * 2;                         // 2 N-tiles per wave
        for (int nt = 0; nt < 2; ++nt) {
            const int dc = (ntb + nt) * 16 + l15;             // output dim d
            const unsigned short* wt = W1T + dc * 136 + q * 8; // B[k=j][n=d]=W1[j][d]
            f32x4 gs = {0.f, 0.f, 0.f, 0.f};
            gs = MFMA16(ga0, ld8(wt), gs);
            gs = MFMA16(ga1, ld8(wt + 32), gs);
            gs = MFMA16(ga2, ld8(wt + 64), gs);
            gs = MFMA16(ga3, ld8(wt + 96), gs);
            const unsigned short* wfp = Wfb + dc * 72 + q * 8; // B[k][n=i]=Wf[i][k]
            f32x4 av = {0.f, 0.f, 0.f, 0.f};
            av = MFMA16(za0, ld8(wfp), av);
            av = MFMA16(za1, ld8(wfp + 32), av);
            const bool  lo  = dc < 32;                        // wave-uniform per nt
            const int   src = lo ? dc + 32 : dc - 32;
            const float sgn = lo ? 1.f : -1.f;
            #pragma unroll
            for (int r = 0; r < 4; ++r) {
                const int rr = row0 + mt * 16 + q * 4 + r;    // global row
                float rev = sgn * z[(size_t)rr * Dd + src];   // fp32-exact reversible
                float a = av[r];
                out[(size_t)rr * Dd + dc] = rev + a * a * gs[r];
            }
        }
    }
}

extern "C" void kernel_launch(void* const* d_in, const int* in_sizes, int n_in,
                              void* d_out, int out_size, void* d_ws, size_t ws_size,
                              hipStream_t stream)
{
    const float* z  = (const float*)d_in[0];
    const float* W1 = (const float*)d_in[1];
    const float* b1 = (const float*)d_in[2];
    const float* W2 = (const float*)d_in[3];
    // d_in[4] = b2: unused — gradient w.r.t. z is independent of b2
    const float* Wf = (const float*)d_in[5];
    float* out = (float*)d_out;
    gnl_kernel<<<Bn / MT, 256, 0, stream>>>(z, W1, b1, W2, Wf, out);
}

// Round 2
// 68.417 us; speedup vs baseline: 1.0079x; 1.0079x over previous
//
#include <hip/hip_runtime.h>
#include <hip/hip_bf16.h>

typedef __bf16 bf16x8 __attribute__((ext_vector_type(8)));
typedef float  f32x4  __attribute__((ext_vector_type(4)));

#define MFMA16(a,b,c) __builtin_amdgcn_mfma_f32_16x16x32_bf16((a),(b),(c),0,0,0)

constexpr int Bn = 8192, Dd = 64, MT = 16;

// ws image layout (bytes): a ready-made LDS image, DMA'd verbatim per block.
//   W1b [128][72]us @0       (GEMM1 B-frags, row-major W1[j][d], pitch 72)
//   Wfb [64][72]us  @18432   (GEMM3 B-frags, row-major Wf[i][d])
//   W1T [64][136]us @27648   (GEMM2 B-frags, W1T[d][j])
//   b1  [128]f32    @45056
//   W2  [128]f32    @45568
constexpr int OFF_WFB = 18432, OFF_W1T = 27648, OFF_B1 = 45056;
constexpr int IMG_BYTES  = 46080;
constexpr int IMG_CHUNKS = IMG_BYTES / 1024;   // 45 wave-chunks (64 lanes x 16B)

__device__ __forceinline__ unsigned short f2bf(float f) {
    unsigned int u = __builtin_bit_cast(unsigned int, f);
    u = (u + 0x7FFFu + ((u >> 16) & 1u)) >> 16;   // RNE
    return (unsigned short)u;
}

__device__ __forceinline__ void gload_lds16(const void* g, void* l) {
    __builtin_amdgcn_global_load_lds(
        (const __attribute__((address_space(1))) unsigned int*)g,
        (__attribute__((address_space(3))) unsigned int*)l, 16, 0, 0);
}

// One-time (per call) weight repack: fp32 -> bf16 LDS image in ws.
// 3328 work items: 2048 (W1 float4) + 1024 (Wf float4) + 128 + 128 (b1/W2).
__global__ __launch_bounds__(256) void prep_kernel(
    const float* __restrict__ W1, const float* __restrict__ b1,
    const float* __restrict__ W2, const float* __restrict__ Wf,
    unsigned short* __restrict__ ws)
{
    int i = blockIdx.x * 256 + threadIdx.x;
    unsigned short* W1b = ws;
    unsigned short* Wfb = ws + OFF_WFB / 2;
    unsigned short* W1T = ws + OFF_W1T / 2;
    float* bw = (float*)(ws + OFF_B1 / 2);
    if (i < 2048) {
        float4 v = ((const float4*)W1)[i];
        int e = i << 2, j = e >> 6, d = e & 63;
        unsigned short c0 = f2bf(v.x), c1 = f2bf(v.y), c2 = f2bf(v.z), c3 = f2bf(v.w);
        *(ushort4*)(W1b + j * 72 + d) = make_ushort4(c0, c1, c2, c3);
        W1T[(d + 0) * 136 + j] = c0;
        W1T[(d + 1) * 136 + j] = c1;
        W1T[(d + 2) * 136 + j] = c2;
        W1T[(d + 3) * 136 + j] = c3;
    } else if (i < 3072) {
        int k = i - 2048;
        float4 v = ((const float4*)Wf)[k];
        int e = k << 2, j = e >> 6, d = e & 63;
        *(ushort4*)(Wfb + j * 72 + d) =
            make_ushort4(f2bf(v.x), f2bf(v.y), f2bf(v.z), f2bf(v.w));
    } else if (i < 3200) {
        bw[i - 3072] = b1[i - 3072];
    } else if (i < 3328) {
        bw[128 + i - 3200] = W2[i - 3200];
    }
}

__global__ __launch_bounds__(256) void gnl_kernel(
    const float* __restrict__ z, const unsigned short* __restrict__ wsimg,
    float* __restrict__ out)
{
    __shared__ unsigned short sh[26368];               // 52736 B -> 2 blocks/CU
    unsigned short* W1b = sh;                          // [128][72]
    unsigned short* Wfb = sh + 9216;                   // [64][72]
    unsigned short* W1T = sh + 13824;                  // [64][136]
    const float* b1f = (const float*)(sh + 22528);     // 128 f32
    const float* w2f = (const float*)(sh + 22784);     // 128 f32
    unsigned short* Zb = sh + 23040;                   // [16][72]
    unsigned short* Gb = sh + 24192;                   // [16][136]

    const int tid  = threadIdx.x;
    const int lane = tid & 63, wv = tid >> 6;
    const int l15 = lane & 15, q = lane >> 4;
    const int row0 = blockIdx.x * MT;

    // ---- stage: weight image via direct-to-LDS DMA (no VALU, no conflicts) ----
    for (int c = wv; c < IMG_CHUNKS; c += 4) {         // wave-uniform trip count
        gload_lds16((const char*)wsimg + c * 1024 + lane * 16,
                    (char*)sh + c * 1024);             // wave-uniform LDS base
    }
    // ---- stage: z tile fp32 -> bf16 (256 float4, exactly 1 per thread) ----
    {
        float4 v = ((const float4*)(z + (size_t)row0 * Dd))[tid];
        int e = tid << 2, r = e >> 6, d = e & 63;
        *(ushort4*)(Zb + r * 72 + d) =
            make_ushort4(f2bf(v.x), f2bf(v.y), f2bf(v.z), f2bf(v.w));
    }
    __syncthreads();

    // A-frags from Z (shared by GEMM1 and GEMM3): A[m=l15][k=q*8+j]
    const int zoff = l15 * 72 + q * 8;
    bf16x8 za0 = *(const bf16x8*)(Zb + zoff);
    bf16x8 za1 = *(const bf16x8*)(Zb + zoff + 32);

    // ---- GEMM1: U = Z*W1^T (K=64), fused g = W2*silu'(u+b1) -> Gb ----
    for (int nt = 0; nt < 2; ++nt) {
        const int jc = (wv * 2 + nt) * 16 + l15;       // column j of U
        const unsigned short* wp = W1b + jc * 72 + q * 8;
        f32x4 acc = {0.f, 0.f, 0.f, 0.f};
        acc = MFMA16(za0, *(const bf16x8*)wp, acc);
        acc = MFMA16(za1, *(const bf16x8*)(wp + 32), acc);
        const float bj = b1f[jc], w2j = w2f[jc];
        #pragma unroll
        for (int r = 0; r < 4; ++r) {                  // C: row=q*4+r, col=jc
            float u = acc[r] + bj;
            float s = 1.f / (1.f + __expf(-u));
            float g = w2j * (s * (1.f + u * (1.f - s)));   // W2 * silu'(u)
            Gb[(q * 4 + r) * 136 + jc] = f2bf(g);
        }
    }
    __syncthreads();

    // ---- GEMM2: GS = G*W1 (K=128); GEMM3: A = Z*Wf^T (K=64); epilogue ----
    {
        const int goff = l15 * 136 + q * 8;
        bf16x8 ga0 = *(const bf16x8*)(Gb + goff);
        bf16x8 ga1 = *(const bf16x8*)(Gb + goff + 32);
        bf16x8 ga2 = *(const bf16x8*)(Gb + goff + 64);
        bf16x8 ga3 = *(const bf16x8*)(Gb + goff + 96);
        const int dc = wv * 16 + l15;                  // output dim d (1 tile/wave)
        const unsigned short* wt = W1T + dc * 136 + q * 8;
        f32x4 gs = {0.f, 0.f, 0.f, 0.f};
        gs = MFMA16(ga0, *(const bf16x8*)wt, gs);
        gs = MFMA16(ga1, *(const bf16x8*)(wt + 32), gs);
        gs = MFMA16(ga2, *(const bf16x8*)(wt + 64), gs);
        gs = MFMA16(ga3, *(const bf16x8*)(wt + 96), gs);
        const unsigned short* wfp = Wfb + dc * 72 + q * 8;
        f32x4 av = {0.f, 0.f, 0.f, 0.f};
        av = MFMA16(za0, *(const bf16x8*)wfp, av);
        av = MFMA16(za1, *(const bf16x8*)(wfp + 32), av);
        const bool  lo  = dc < 32;                     // wave-uniform (16-col tile)
        const int   src = lo ? dc + 32 : dc - 32;
        const float sgn = lo ? 1.f : -1.f;
        #pragma unroll
        for (int r = 0; r < 4; ++r) {
            const int rr = row0 + q * 4 + r;           // global row
            float rev = sgn * z[(size_t)rr * Dd + src];    // fp32-exact reversible
            float a = av[r];
            out[(size_t)rr * Dd + dc] = rev + a * a * gs[r];
        }
    }
}

extern "C" void kernel_launch(void* const* d_in, const int* in_sizes, int n_in,
                              void* d_out, int out_size, void* d_ws, size_t ws_size,
                              hipStream_t stream)
{
    const float* z  = (const float*)d_in[0];
    const float* W1 = (const float*)d_in[1];
    const float* b1 = (const float*)d_in[2];
    const float* W2 = (const float*)d_in[3];
    // d_in[4] = b2: unused — gradient w.r.t. z is independent of b2
    const float* Wf = (const float*)d_in[5];
    float* out = (float*)d_out;
    unsigned short* ws = (unsigned short*)d_ws;

    prep_kernel<<<13, 256, 0, stream>>>(W1, b1, W2, Wf, ws);
    gnl_kernel<<<Bn / MT, 256, 0, stream>>>(z, ws, out);
}

// Round 3
// 67.687 us; speedup vs baseline: 1.0187x; 1.0108x over previous
//
#include <hip/hip_runtime.h>
#include <hip/hip_bf16.h>

typedef __bf16 bf16x8 __attribute__((ext_vector_type(8)));
typedef float  f32x4  __attribute__((ext_vector_type(4)));

#define MFMA16(a,b,c) __builtin_amdgcn_mfma_f32_16x16x32_bf16((a),(b),(c),0,0,0)

constexpr int Bn = 8192, Dd = 64, MT = 32;

// ws image layout (bytes): ready-made LDS image, DMA'd verbatim per block.
//   W1b [128][72]us @0       (GEMM1 B-frags, row-major W1[j][d], pitch 72)
//   Wfb [64][72]us  @18432   (GEMM3 B-frags, row-major Wf[i][d])
//   W1T [64][136]us @27648   (GEMM2 B-frags, W1T[d][j])
//   b1  [128]f32    @45056
//   W2  [128]f32    @45568
constexpr int OFF_WFB = 18432, OFF_W1T = 27648, OFF_B1 = 45056;
constexpr int IMG_BYTES  = 46080;
constexpr int IMG_CHUNKS = IMG_BYTES / 1024;   // 45 wave-chunks (64 lanes x 16B)

__device__ __forceinline__ unsigned short f2bf(float f) {
    unsigned int u = __builtin_bit_cast(unsigned int, f);
    u = (u + 0x7FFFu + ((u >> 16) & 1u)) >> 16;   // RNE
    return (unsigned short)u;
}

__device__ __forceinline__ void gload_lds16(const void* g, void* l) {
    __builtin_amdgcn_global_load_lds(
        (const __attribute__((address_space(1))) unsigned int*)g,
        (__attribute__((address_space(3))) unsigned int*)l, 16, 0, 0);
}

// One-time (per call) weight repack: fp32 -> bf16 LDS image in ws.
__global__ __launch_bounds__(256) void prep_kernel(
    const float* __restrict__ W1, const float* __restrict__ b1,
    const float* __restrict__ W2, const float* __restrict__ Wf,
    unsigned short* __restrict__ ws)
{
    int i = blockIdx.x * 256 + threadIdx.x;
    unsigned short* W1b = ws;
    unsigned short* Wfb = ws + OFF_WFB / 2;
    unsigned short* W1T = ws + OFF_W1T / 2;
    float* bw = (float*)(ws + OFF_B1 / 2);
    if (i < 2048) {
        float4 v = ((const float4*)W1)[i];
        int e = i << 2, j = e >> 6, d = e & 63;
        unsigned short c0 = f2bf(v.x), c1 = f2bf(v.y), c2 = f2bf(v.z), c3 = f2bf(v.w);
        *(ushort4*)(W1b + j * 72 + d) = make_ushort4(c0, c1, c2, c3);
        W1T[(d + 0) * 136 + j] = c0;
        W1T[(d + 1) * 136 + j] = c1;
        W1T[(d + 2) * 136 + j] = c2;
        W1T[(d + 3) * 136 + j] = c3;
    } else if (i < 3072) {
        int k = i - 2048;
        float4 v = ((const float4*)Wf)[k];
        int e = k << 2, j = e >> 6, d = e & 63;
        *(ushort4*)(Wfb + j * 72 + d) =
            make_ushort4(f2bf(v.x), f2bf(v.y), f2bf(v.z), f2bf(v.w));
    } else if (i < 3200) {
        bw[i - 3072] = b1[i - 3072];
    } else if (i < 3328) {
        bw[128 + i - 3200] = W2[i - 3200];
    }
}

// LDS map (ushort units): image @0..23039, then Zb, Gb. 59392 B total.
__global__ __launch_bounds__(256) void gnl_kernel(
    const float* __restrict__ z, const unsigned short* __restrict__ wsimg,
    float* __restrict__ out)
{
    __shared__ unsigned short sh[29696];
    unsigned short* W1b = sh;                          // [128][72]
    unsigned short* Wfb = sh + 9216;                   // [64][72]
    unsigned short* W1T = sh + 13824;                  // [64][136]
    const float* b1f = (const float*)(sh + 22528);     // 128 f32
    const float* w2f = (const float*)(sh + 22784);     // 128 f32
    unsigned short* Zb = sh + 23040;                   // [32][72]
    unsigned short* Gb = sh + 25344;                   // [32][136]

    const int tid  = threadIdx.x;
    const int lane = tid & 63, wv = tid >> 6;
    const int l15 = lane & 15, q = lane >> 4;
    const int row0 = blockIdx.x * MT;

    // ---- stage: weight image via direct-to-LDS DMA (no VALU, no conflicts) ----
    for (int c = wv; c < IMG_CHUNKS; c += 4) {         // wave-uniform trip count
        gload_lds16((const char*)wsimg + c * 1024 + lane * 16,
                    (char*)sh + c * 1024);             // wave-uniform LDS base
    }
    // ---- stage: z tile fp32 -> bf16 (512 float4, 2 per thread) ----
    for (int i = tid; i < (MT * Dd) / 4; i += 256) {
        float4 v = ((const float4*)(z + (size_t)row0 * Dd))[i];
        int e = i << 2, r = e >> 6, d = e & 63;
        *(ushort4*)(Zb + r * 72 + d) =
            make_ushort4(f2bf(v.x), f2bf(v.y), f2bf(v.z), f2bf(v.w));
    }
    __syncthreads();

    const int mt = wv & 1;                             // 16-row sub-tile

    // A-frags from Z (shared by GEMM1 and GEMM3): A[m=l15][k=q*8+j]
    const int zoff = (mt * 16 + l15) * 72 + q * 8;
    bf16x8 za0 = *(const bf16x8*)(Zb + zoff);
    bf16x8 za1 = *(const bf16x8*)(Zb + zoff + 32);

    // ---- GEMM1: U = Z*W1^T (K=64), fused g = W2*silu'(u+b1) -> Gb ----
    {
        const int ntb = (wv >> 1) * 4;                 // 4 N-tiles per wave
        for (int nt = 0; nt < 4; ++nt) {
            const int jc = (ntb + nt) * 16 + l15;      // column j of U
            const unsigned short* wp = W1b + jc * 72 + q * 8;
            f32x4 acc = {0.f, 0.f, 0.f, 0.f};
            acc = MFMA16(za0, *(const bf16x8*)wp, acc);
            acc = MFMA16(za1, *(const bf16x8*)(wp + 32), acc);
            const float bj = b1f[jc], w2j = w2f[jc];
            #pragma unroll
            for (int r = 0; r < 4; ++r) {              // C: row=q*4+r, col=jc
                float u = acc[r] + bj;
                float s = 1.f / (1.f + __expf(-u));
                float g = w2j * (s * (1.f + u * (1.f - s)));  // W2 * silu'(u)
                Gb[(mt * 16 + q * 4 + r) * 136 + jc] = f2bf(g);
            }
        }
    }
    __syncthreads();

    // ---- GEMM2: GS = G*W1 (K=128); GEMM3: A = Z*Wf^T (K=64); epilogue ----
    {
        const int goff = (mt * 16 + l15) * 136 + q * 8;
        bf16x8 ga0 = *(const bf16x8*)(Gb + goff);
        bf16x8 ga1 = *(const bf16x8*)(Gb + goff + 32);
        bf16x8 ga2 = *(const bf16x8*)(Gb + goff + 64);
        bf16x8 ga3 = *(const bf16x8*)(Gb + goff + 96);
        const int ntb = (wv >> 1) * 2;                 // 2 N-tiles per wave
        for (int nt = 0; nt < 2; ++nt) {
            const int dc = (ntb + nt) * 16 + l15;      // output dim d
            const unsigned short* wt = W1T + dc * 136 + q * 8;
            f32x4 gs = {0.f, 0.f, 0.f, 0.f};
            gs = MFMA16(ga0, *(const bf16x8*)wt, gs);
            gs = MFMA16(ga1, *(const bf16x8*)(wt + 32), gs);
            gs = MFMA16(ga2, *(const bf16x8*)(wt + 64), gs);
            gs = MFMA16(ga3, *(const bf16x8*)(wt + 96), gs);
            const unsigned short* wfp = Wfb + dc * 72 + q * 8;
            f32x4 av = {0.f, 0.f, 0.f, 0.f};
            av = MFMA16(za0, *(const bf16x8*)wfp, av);
            av = MFMA16(za1, *(const bf16x8*)(wfp + 32), av);
            const bool  lo  = dc < 32;                 // wave-uniform per nt
            const int   src = lo ? dc + 32 : dc - 32;
            const float sgn = lo ? 1.f : -1.f;
            #pragma unroll
            for (int r = 0; r < 4; ++r) {
                const int rr = row0 + mt * 16 + q * 4 + r;   // global row
                float rev = sgn * z[(size_t)rr * Dd + src];  // fp32-exact reversible
                float a = av[r];
                out[(size_t)rr * Dd + dc] = rev + a * a * gs[r];
            }
        }
    }
}

extern "C" void kernel_launch(void* const* d_in, const int* in_sizes, int n_in,
                              void* d_out, int out_size, void* d_ws, size_t ws_size,
                              hipStream_t stream)
{
    const float* z  = (const float*)d_in[0];
    const float* W1 = (const float*)d_in[1];
    const float* b1 = (const float*)d_in[2];
    const float* W2 = (const float*)d_in[3];
    // d_in[4] = b2: unused — gradient w.r.t. z is independent of b2
    const float* Wf = (const float*)d_in[5];
    float* out = (float*)d_out;
    unsigned short* ws = (unsigned short*)d_ws;

    prep_kernel<<<13, 256, 0, stream>>>(W1, b1, W2, Wf, ws);
    gnl_kernel<<<Bn / MT, 256, 0, stream>>>(z, ws, out);
}